// Round 1
// baseline (139.843 us; speedup 1.0000x reference)
//
#include <hip/hip_runtime.h>
#include <math.h>

// contracting REN forward.
// Sizes: S=8 (state), N=64 (neurons), NU=6, NY=5, NH=2*S+N=80.
// B = 524288 rows. Outputs: hidden (B,8) then y (B,5), concatenated flat.

constexpr int S  = 8;
constexpr int N  = 64;
constexpr int NU = 6;
constexpr int NY = 5;
constexpr int NH = 80;

// workspace layout (float offsets)
constexpr int WS_H    = 0;            // 80*80 = 6400
constexpr int WS_C1F  = 6400;         // 64*8  (C1 / Lambda)
constexpr int WS_D12F = 6912;         // 64*6  (calD_12 / Lambda)
constexpr int WS_BWF  = 7296;         // 64    (bw / Lambda)
constexpr int WS_DT   = 7360;         // 64*64 (Dtilde, strictly lower)
constexpr int WS_G1   = 11456;        // 8*8   (Einv @ F_)
constexpr int WS_G2   = 11520;        // 8*64  (Einv @ B1)
constexpr int WS_G3   = 12032;        // 8*6   (Einv @ calB_2)
constexpr int WS_G4   = 12080;        // 8     (Einv @ bx)
constexpr int WS_E    = 12088;        // 8*8
constexpr int WS_EINV = 12152;        // 8*8
// total 12216 floats ~= 49 KB

__global__ void k_gram(const float* __restrict__ X, float* __restrict__ ws) {
    int idx = blockIdx.x * blockDim.x + threadIdx.x;
    if (idx >= NH * NH) return;
    int a = idx / NH, b = idx % NH;
    float acc = 0.f;
    for (int k = 0; k < NH; k++) acc += X[k * NH + a] * X[k * NH + b];
    if (a == b) acc += 1e-4f;
    ws[WS_H + idx] = acc;
}

__global__ void k_derive(const float* __restrict__ calB2,
                         const float* __restrict__ calD12,
                         const float* __restrict__ Y1,
                         const float* __restrict__ bias,
                         float* __restrict__ ws) {
    int tid = threadIdx.x;  // 1 block x 256 threads
    const float* H = ws + WS_H;

    // E = 0.5*(H11 + calP + Y1)
    if (tid < 64) {
        int a = tid >> 3, b = tid & 7;
        ws[WS_E + tid] = 0.5f * (H[a * NH + b] + H[(72 + a) * NH + 72 + b] + Y1[a * 8 + b]);
    }
    __syncthreads();

    // Einv: 8x8 Gauss-Jordan with partial pivoting (single thread, tiny)
    if (tid == 0) {
        float M[8][16];
        for (int i = 0; i < 8; i++)
            for (int j = 0; j < 8; j++) {
                M[i][j] = ws[WS_E + i * 8 + j];
                M[i][8 + j] = (i == j) ? 1.f : 0.f;
            }
        for (int p = 0; p < 8; p++) {
            int pr = p; float best = fabsf(M[p][p]);
            for (int r = p + 1; r < 8; r++) {
                float v = fabsf(M[r][p]);
                if (v > best) { best = v; pr = r; }
            }
            if (pr != p)
                for (int c = 0; c < 16; c++) { float t = M[p][c]; M[p][c] = M[pr][c]; M[pr][c] = t; }
            float inv = 1.f / M[p][p];
            for (int c = 0; c < 16; c++) M[p][c] *= inv;
            for (int r = 0; r < 8; r++) {
                if (r == p) continue;
                float f = M[r][p];
                for (int c = 0; c < 16; c++) M[r][c] -= f * M[p][c];
            }
        }
        for (int i = 0; i < 8; i++)
            for (int j = 0; j < 8; j++) ws[WS_EINV + i * 8 + j] = M[i][8 + j];
    }
    __syncthreads();

    const float* Einv = ws + WS_EINV;

    // Dtilde = -tril(H22,-1)/Lambda ;  Lambda[i] = 0.5*H22[i][i]
    for (int idx = tid; idx < 64 * 64; idx += 256) {
        int i = idx >> 6, j = idx & 63;
        float lam = 0.5f * H[(8 + i) * NH + 8 + i];
        ws[WS_DT + idx] = (j < i) ? (-H[(8 + i) * NH + 8 + j] / lam) : 0.f;
    }
    // C1f = -H[8+i][s]/Lambda[i]
    for (int idx = tid; idx < 64 * 8; idx += 256) {
        int i = idx >> 3, s2 = idx & 7;
        float lam = 0.5f * H[(8 + i) * NH + 8 + i];
        ws[WS_C1F + idx] = -H[(8 + i) * NH + s2] / lam;
    }
    // D12f = calD_12/Lambda
    for (int idx = tid; idx < 64 * 6; idx += 256) {
        int i = idx / 6;
        float lam = 0.5f * H[(8 + i) * NH + 8 + i];
        ws[WS_D12F + idx] = calD12[idx] / lam;
    }
    // bwf = bw/Lambda
    if (tid < 64) {
        float lam = 0.5f * H[(8 + tid) * NH + 8 + tid];
        ws[WS_BWF + tid] = bias[8 + tid] / lam;
    }
    // G1 = Einv @ F_   (F_[k][s] = H[72+k][s])
    if (tid < 64) {
        int a = tid >> 3, s2 = tid & 7;
        float acc = 0.f;
        for (int k = 0; k < 8; k++) acc += Einv[a * 8 + k] * H[(72 + k) * NH + s2];
        ws[WS_G1 + tid] = acc;
    }
    // G2 = Einv @ B1   (B1[k][j] = H[72+k][8+j])
    for (int idx = tid; idx < 512; idx += 256) {
        int a = idx >> 6, j = idx & 63;
        float acc = 0.f;
        for (int k = 0; k < 8; k++) acc += Einv[a * 8 + k] * H[(72 + k) * NH + 8 + j];
        ws[WS_G2 + idx] = acc;
    }
    // G3 = Einv @ calB_2
    if (tid < 48) {
        int a = tid / 6, c = tid % 6;
        float acc = 0.f;
        for (int k = 0; k < 8; k++) acc += Einv[a * 8 + k] * calB2[k * 6 + c];
        ws[WS_G3 + tid] = acc;
    }
    // g4 = Einv @ bx
    if (tid < 8) {
        float acc = 0.f;
        for (int k = 0; k < 8; k++) acc += Einv[tid * 8 + k] * bias[k];
        ws[WS_G4 + tid] = acc;
    }
}

__device__ __forceinline__ float fast_tanh(float x) {
    x = fminf(fmaxf(x, -15.f), 15.f);
    float e = __expf(2.f * x);                       // v_mul + v_exp_f32
    return 1.f - 2.f * __builtin_amdgcn_rcpf(e + 1.f);
}

__global__ __launch_bounds__(256) void k_main(
    const float* __restrict__ xg, const float* __restrict__ ug,
    const float* __restrict__ C2, const float* __restrict__ D21,
    const float* __restrict__ D22, const float* __restrict__ bias,
    const float* __restrict__ ws, float* __restrict__ out, int B)
{
    int t = blockIdx.x * blockDim.x + threadIdx.x;
    if (t >= B) return;

    float xv[8], uv[6];
    const float4* xp = reinterpret_cast<const float4*>(xg + (size_t)t * 8);
    float4 x0 = xp[0], x1 = xp[1];
    xv[0] = x0.x; xv[1] = x0.y; xv[2] = x0.z; xv[3] = x0.w;
    xv[4] = x1.x; xv[5] = x1.y; xv[6] = x1.z; xv[7] = x1.w;
    const float2* up = reinterpret_cast<const float2*>(ug + (size_t)t * 6);
    float2 u0 = up[0], u1 = up[1], u2 = up[2];
    uv[0] = u0.x; uv[1] = u0.y; uv[2] = u1.x; uv[3] = u1.y; uv[4] = u2.x; uv[5] = u2.y;

    const float* C1f  = ws + WS_C1F;
    const float* D12f = ws + WS_D12F;
    const float* bwf  = ws + WS_BWF;
    const float* Dt   = ws + WS_DT;
    const float* G1   = ws + WS_G1;
    const float* G2   = ws + WS_G2;
    const float* G3   = ws + WS_G3;
    const float* g4   = ws + WS_G4;

    // v0 (with bw and 1/Lambda folded in)
    float w[64];
    #pragma unroll
    for (int i = 0; i < 64; i++) {
        float acc = bwf[i];
        #pragma unroll
        for (int s2 = 0; s2 < 8; s2++) acc += xv[s2] * C1f[i * 8 + s2];
        #pragma unroll
        for (int c = 0; c < 6; c++) acc += uv[c] * D12f[i * 6 + c];
        w[i] = acc;
    }
    // sequential triangular tanh scan: w[i] = tanh(v0[i] + sum_{j<i} Dt[i][j]*w[j])
    #pragma unroll
    for (int i = 0; i < 64; i++) {
        float acc = w[i];
        #pragma unroll
        for (int j = 0; j < i; j++) acc += Dt[i * 64 + j] * w[j];
        w[i] = fast_tanh(acc);
    }
    // hidden = x@G1.T + w@G2.T + u@G3.T + g4   (Einv folded)
    float h[8];
    #pragma unroll
    for (int a = 0; a < 8; a++) {
        float acc = g4[a];
        #pragma unroll
        for (int s2 = 0; s2 < 8; s2++) acc += xv[s2] * G1[a * 8 + s2];
        #pragma unroll
        for (int c = 0; c < 6; c++) acc += uv[c] * G3[a * 6 + c];
        #pragma unroll
        for (int j = 0; j < 64; j++) acc += w[j] * G2[a * 64 + j];
        h[a] = acc;
    }
    float4* hp = reinterpret_cast<float4*>(out + (size_t)t * 8);
    hp[0] = make_float4(h[0], h[1], h[2], h[3]);
    hp[1] = make_float4(h[4], h[5], h[6], h[7]);

    // y = x@C2.T + w@D21.T + u@D22.T + by
    float* yp = out + (size_t)B * 8 + (size_t)t * 5;
    #pragma unroll
    for (int q = 0; q < 5; q++) {
        float acc = bias[72 + q];
        #pragma unroll
        for (int s2 = 0; s2 < 8; s2++) acc += xv[s2] * C2[q * 8 + s2];
        #pragma unroll
        for (int c = 0; c < 6; c++) acc += uv[c] * D22[q * 6 + c];
        #pragma unroll
        for (int j = 0; j < 64; j++) acc += w[j] * D21[q * 64 + j];
        yp[q] = acc;
    }
}

extern "C" void kernel_launch(void* const* d_in, const int* in_sizes, int n_in,
                              void* d_out, int out_size, void* d_ws, size_t ws_size,
                              hipStream_t stream) {
    const float* x      = (const float*)d_in[0];
    const float* u      = (const float*)d_in[1];
    const float* X      = (const float*)d_in[2];
    const float* calB2  = (const float*)d_in[3];
    const float* C2     = (const float*)d_in[4];
    const float* calD12 = (const float*)d_in[5];
    const float* D21    = (const float*)d_in[6];
    const float* D22    = (const float*)d_in[7];
    const float* Y1     = (const float*)d_in[8];
    const float* bias   = (const float*)d_in[9];
    float* ws  = (float*)d_ws;
    float* out = (float*)d_out;
    int B = in_sizes[0] / 8;

    k_gram<<<(NH * NH + 255) / 256, 256, 0, stream>>>(X, ws);
    k_derive<<<1, 256, 0, stream>>>(calB2, calD12, Y1, bias, ws);
    k_main<<<(B + 255) / 256, 256, 0, stream>>>(x, u, C2, D21, D22, bias, ws, out, B);
}